// Round 4
// baseline (89.422 us; speedup 1.0000x reference)
//
#include <hip/hip_runtime.h>
#include <hip/hip_bf16.h>

typedef __attribute__((ext_vector_type(8))) short short8;   // 8 bf16 (4 VGPRs)
typedef __attribute__((ext_vector_type(4))) float f32x4;
typedef unsigned int uint;
typedef __attribute__((ext_vector_type(4))) uint uint4v;    // align 16 -> dwordx4/b128

#define AS1 __attribute__((address_space(1)))
#define AS3 __attribute__((address_space(3)))

// ws: Rp4 [0,1MB) | Qp4 [1MB,1.25MB) | xph [1.25MB, +34.1MB)
#define QB_OFF  (1u << 20)
#define XPH_OFF (1310720u)
// xph byte addr: n*1115136 + row*16896 + col*256 + c*2   (row,col in 0..65, c in 0..127)
// Rp4: [s 0..63][cu 0..3][col 0..255]*16B ; holds R[col][k=s*32+cu*8+e]
//      (k-order: g=k>>7 window, c=k&127; f=c*16+g)
// Qp4: [ks 0..7][col 0..511][cu 0..3]*16B ; Q[col][ks*32+cu*8+e]

__device__ __forceinline__ uint bf16r(float f) {
    uint u = __float_as_uint(f);
    u += 0x7FFFu + ((u >> 16) & 1u);
    return u >> 16;
}
__device__ __forceinline__ uint pk2(float lo, float hi) {
    return bf16r(lo) | (bf16r(hi) << 16);
}

// ---------------- prep: NHWC-padded bf16 x, [cu][col] R slabs, Q K-slabs ----------------
__global__ __launch_bounds__(256) void prep_kernel(
    const float* __restrict__ x, const float* __restrict__ Q, const float* __restrict__ R,
    char* __restrict__ Rp4, char* __restrict__ Qp4, char* __restrict__ xph)
{
    const int bid = blockIdx.x, tid = threadIdx.x;
    if (bid < 2048) {                       // transpose: n = bid>>6, h = bid&63
        __shared__ float xt[128 * 65];
        const int n = bid >> 6, h = bid & 63;
        {   // read x[n][c][h][w] coalesced, stage to LDS
            const int c = tid >> 1, half = tid & 1;
            const float4* src = (const float4*)(x + (((size_t)(n * 128 + c) * 64 + h) * 64 + half * 32));
            #pragma unroll
            for (int q = 0; q < 8; ++q) {
                float4 v = src[q];
                float* d = &xt[c * 65 + half * 32 + q * 4];
                d[0] = v.x; d[1] = v.y; d[2] = v.z; d[3] = v.w;
            }
        }
        __syncthreads();
        {   // write xph[n][h+1][w+1][c] (32 channels per thread)
            const int w = tid >> 2, cq = tid & 3;
            uint pw[16];
            #pragma unroll
            for (int m = 0; m < 16; ++m)
                pw[m] = pk2(xt[(cq * 32 + 2 * m) * 65 + w], xt[(cq * 32 + 2 * m + 1) * 65 + w]);
            char* dst = xph + (size_t)n * 1115136 + (size_t)(h + 1) * 16896 + (w + 1) * 256 + cq * 64;
            #pragma unroll
            for (int i = 0; i < 4; ++i) {
                uint4v q4 = { pw[4 * i], pw[4 * i + 1], pw[4 * i + 2], pw[4 * i + 3] };
                *(uint4v*)(dst + i * 16) = q4;
            }
        }
        if (tid < 32) {                      // col borders 0 and 65
            int side = tid >> 4, e = tid & 15;
            uint4v z = {0, 0, 0, 0};
            *(uint4v*)(xph + (size_t)n * 1115136 + (size_t)(h + 1) * 16896 + side * 65 * 256 + e * 16) = z;
        }
        if (h == 0) {                        // row borders 0 and 65
            uint4v z = {0, 0, 0, 0};
            #pragma unroll
            for (int it = 0; it < 9; ++it) {
                int idx = tid + it * 256;
                if (idx < 2112) {
                    int rr = (idx >= 1056) ? 65 : 0;
                    int jj = idx - (rr ? 1056 : 0);
                    int col = jj >> 4, e = jj & 15;
                    *(uint4v*)(xph + (size_t)n * 1115136 + (size_t)rr * 16896 + col * 256 + e * 16) = z;
                }
            }
        }
    } else if (bid < 2304) {                // R -> Rp4[s][cu][col] (linear dst)
        int g = (bid - 2048) * 256 + tid;   // 0..65535
        int s = g >> 10, rem = g & 1023;
        int cu = rem >> 8, col = rem & 255;
        // k = s*32 + cu*8 + e ; g_win = s>>2 ; c = (s&3)*32 + cu*8 + e ; f = c*16 + g_win
        const float* src = R + (size_t)col * 2048 + (((s & 3) * 32 + cu * 8) * 16 + (s >> 2));
        uint pw[4];
        #pragma unroll
        for (int m = 0; m < 4; ++m)
            pw[m] = pk2(src[(2 * m) * 16], src[(2 * m + 1) * 16]);
        uint4v q4 = { pw[0], pw[1], pw[2], pw[3] };
        *(uint4v*)(Rp4 + (size_t)g * 16) = q4;
    } else {                                 // Q -> Qp4[ks][col][cu] (linear dst)
        int g = (bid - 2304) * 256 + tid;   // 0..16383
        int ks = g >> 11, p = g & 2047;
        int col = p >> 2, cu = p & 3;
        const float4* s = (const float4*)(Q + (size_t)col * 256 + ks * 32 + cu * 8);
        float4 a = s[0], b = s[1];
        uint4v q4 = { pk2(a.x, a.y), pk2(a.z, a.w), pk2(b.x, b.y), pk2(b.z, b.w) };
        *(uint4v*)(Qp4 + (size_t)ks * 32768 + p * 16) = q4;
    }
}

// ---------------- fused: BM=64 x BN=256, 256 thr / 4 waves, LDS 64KB -> 2 blocks/CU ----------------
// Mechanism under test: TWO INDEPENDENT workgroups per CU with uncorrelated barriers/ledgers ->
// when block A stalls at its vmcnt/barrier, block B's waves issue MFMAs (dynamic TLP).
// LDS 64KB/block: X 3x4KB [0,12K) | B 3x16KB [12K,60K) | ttile 32KB [0,32K) after gemm1
//                 | ep [2][128][64] f32 64KB after gemm2 (xor-swizzled, no pad)
// Slab layouts [c-unit][pos/col]: each quarter-wave reads 256B contiguous -> conflict-free b128.
// Ledger: batch(s) = {B(s):4, X(s):1} = 5 loads/thread. Issue batch s+2 at phase s; barrier
// drains batch s+1 -> vmcnt(5) keeps batch s+2 in flight.
__global__ __launch_bounds__(256, 2) void fused_kernel(
    const char* __restrict__ xph, const char* __restrict__ Rp4,
    const char* __restrict__ Qp4, float* __restrict__ out)
{
    extern __shared__ __align__(16) char lds[];

    const int blk = blockIdx.x;
    const int b = (blk & 7) * 64 + (blk >> 3);  // XCD-contiguous swizzle (512%8==0)
    const int n = b >> 4, vt = b & 15;          // vt: 4 output-row block (r = vt*4 + p*2 + si)
    const int tid = threadIdx.x;
    const int wave = tid >> 6, lane = tid & 63;
    const int lr = lane & 15, kg = lane >> 4;
    const int lr7 = lr & 7;
    const int wn = wave;                        // gemm1 col group; gemm2 (si = wn>>1, ochalf = wn&1)

    const char* xbase = xph + (size_t)n * 1115136;
    const int u16 = tid * 16;

    // X DMA: c-unit = wave, pos = lane  (slab [cu 0..3][pos 0..63])
    const int xrh = lane >> 5, xcl = lane & 31;
    const int xc0 = (4 * vt + 2 * xrh) * 16896 + (2 * xcl) * 256 + wave * 16;

    // gemm1 fragment read bases ([cu][pos]/[cu][col] layouts, conflict-free)
    const int a0  = kg * 1024 + lr * 16;                      // af[mf] = a0 + mf*256
    const int bb0 = kg * 4096 + wn * 1024 + lr * 16;          // bf[nf] = bb0 + nf*256

    // ttile [ru 0..31][pos 0..63]*16B: entry (ru,pos) holds T[pos][ru*8+e]
    // write addr = (wn*8 + nf*2 + (lr>>3))*1024 + (mf*16+kg*4+r)*16 + (lr&7)*2
    const int t0 = (wn * 8 + (lr >> 3)) * 1024 + (lr & 7) * 2;   // FIX: no kg*64 here

    // gemm2 Q col map (same output mapping as proven R2 epilogue)
    int qoff[8];
    #pragma unroll
    for (int nf = 0; nf < 8; ++nf)
        qoff[nf] = ((wn >> 1) * 256 + (nf >> 2) * 128 + (wn & 1) * 64 + (nf & 3) * 16 + lr) * 64 + kg * 16;

#define BDMA(s_) { _Pragma("unroll") for (int q = 0; q < 4; ++q)                        \
        __builtin_amdgcn_global_load_lds(                                               \
            (const AS1 void*)(Rp4 + (size_t)(s_) * 16384 + q * 4096 + u16),             \
            (AS3 void*)(lds + 12288 + ((s_) % 3) * 16384 + q * 4096 + u16), 16, 0, 0); }
#define XDMA(s_) __builtin_amdgcn_global_load_lds(                                      \
        (const AS1 void*)(xbase + xc0 + ((s_) >> 4) * 16896 + (((s_) >> 2) & 3) * 256 + ((s_) & 3) * 64), \
        (AS3 void*)(lds + ((s_) % 3) * 4096 + u16), 16, 0, 0);

#define BAR(Nstr) { __builtin_amdgcn_sched_barrier(0);                                  \
        asm volatile("s_waitcnt vmcnt(" Nstr ") lgkmcnt(0)\n\ts_barrier" ::: "memory"); \
        __builtin_amdgcn_sched_barrier(0); }
#define LBAR { __builtin_amdgcn_sched_barrier(0);                                       \
        asm volatile("s_waitcnt lgkmcnt(0)\n\ts_barrier" ::: "memory");                 \
        __builtin_amdgcn_sched_barrier(0); }

    f32x4 acc[4][4];
    #pragma unroll
    for (int i = 0; i < 4; ++i)
        #pragma unroll
        for (int j = 0; j < 4; ++j) acc[i][j] = (f32x4)0.f;

    // prologue: batches 0,1 in flight (10); drain batch 0, keep batch 1
    BDMA(0) XDMA(0) BDMA(1) XDMA(1)
    BAR("5")

    // ---- gemm1: 64 phases (one K=32 chunk each), 16 MFMA/wave/phase ----
    #pragma unroll
    for (int s = 0; s < 64; ++s) {
        if (s <= 61) { BDMA(s + 2) XDMA(s + 2) }
        const char* xs = lds + (s % 3) * 4096;
        const char* bs = lds + 12288 + (s % 3) * 16384;
        short8 af[4], bf[4];
        #pragma unroll
        for (int mf = 0; mf < 4; ++mf)
            af[mf] = *(const short8*)(xs + a0 + mf * 256);
        #pragma unroll
        for (int nf = 0; nf < 4; ++nf)
            bf[nf] = *(const short8*)(bs + bb0 + nf * 256);
        __builtin_amdgcn_s_setprio(1);
        #pragma unroll
        for (int nf = 0; nf < 4; ++nf)
            #pragma unroll
            for (int mf = 0; mf < 4; ++mf)
                acc[mf][nf] = __builtin_amdgcn_mfma_f32_16x16x32_bf16(af[mf], bf[nf], acc[mf][nf], 0, 0, 0);
        __builtin_amdgcn_s_setprio(0);
        if (s <= 61) { BAR("5") } else { BAR("0") }
    }

    // ---- ttile: acc -> bf16 [ru 0..31][pos 0..63]*16B at lds+0 (all slabs dead) ----
    #pragma unroll
    for (int mf = 0; mf < 4; ++mf)
        #pragma unroll
        for (int nf = 0; nf < 4; ++nf)
            #pragma unroll
            for (int r = 0; r < 4; ++r) {
                // ru = wn*8 + nf*2 + (lr>>3) ; pos = mf*16 + kg*4 + r ; e = lr&7
                *(ushort*)(lds + t0 + nf * 2048 + (mf * 16 + kg * 4 + r) * 16) =
                    (ushort)bf16r(acc[mf][nf][r]);
            }
    LBAR

    // ---- gemm2: Y[64][512] = ttile @ Q^T ; Q per-wave global b128 (L2-hot), barrier-free ----
    f32x4 acc2[4][8];
    #pragma unroll
    for (int i = 0; i < 4; ++i)
        #pragma unroll
        for (int j = 0; j < 8; ++j) acc2[i][j] = (f32x4)0.f;
    #pragma unroll
    for (int ks = 0; ks < 8; ++ks) {
        short8 af2[4];
        #pragma unroll
        for (int mf = 0; mf < 4; ++mf)
            af2[mf] = *(const short8*)(lds + ks * 4096 + a0 + mf * 256);
        #pragma unroll
        for (int nf = 0; nf < 8; ++nf) {
            const short8 bq = *(const short8*)(Qp4 + (size_t)ks * 32768 + qoff[nf]);
            #pragma unroll
            for (int mf = 0; mf < 4; ++mf)
                acc2[mf][nf] = __builtin_amdgcn_mfma_f32_16x16x32_bf16(af2[mf], bq, acc2[mf][nf], 0, 0, 0);
        }
    }

    // ---- epilogue: 2 passes (p = prow); ep[2 si][128 oc][64 w] f32, 8x32B units xor-swizzled ----
    const int si = wn >> 1, ochalf = wn & 1;
    #pragma unroll
    for (int p = 0; p < 2; ++p) {
        LBAR
        #pragma unroll
        for (int mfh = 0; mfh < 2; ++mfh) {
            const int mf = 2 * p + mfh;
            #pragma unroll
            for (int q = 0; q < 4; ++q) {
                const int oc = ochalf * 64 + q * 16 + lr;          // oc&7 == lr7
                const int ub = si * 32768 + oc * 256 + (((4 * mfh + kg) ^ lr7) << 5);
                // w = 32*mfh + 8*kg + 2*r + sj ; sj=0 -> nf=q, sj=1 -> nf=4+q
                f32x4 v0 = { acc2[mf][q][0], acc2[mf][4 + q][0], acc2[mf][q][1], acc2[mf][4 + q][1] };
                f32x4 v1 = { acc2[mf][q][2], acc2[mf][4 + q][2], acc2[mf][q][3], acc2[mf][4 + q][3] };
                *(f32x4*)(lds + ub) = v0;
                *(f32x4*)(lds + ub + 16) = v1;
            }
        }
        LBAR
        #pragma unroll
        for (int it = 0; it < 16; ++it) {
            int uidx = it * 256 + tid;
            int w4 = uidx & 15, oc = (uidx >> 4) & 127, sie = uidx >> 11;
            f32x4 v = *(const f32x4*)(lds + sie * 32768 + oc * 256 + ((w4 ^ (2 * (oc & 7))) << 4));
            *(f32x4*)(out + (size_t)n * 524288 + (size_t)oc * 4096
                          + (vt * 4 + p * 2 + sie) * 64 + w4 * 4) = v;
        }
    }
}

extern "C" void kernel_launch(void* const* d_in, const int* in_sizes, int n_in,
                              void* d_out, int out_size, void* d_ws, size_t ws_size,
                              hipStream_t stream) {
    const float* x = (const float*)d_in[0];
    const float* Q = (const float*)d_in[1];
    const float* R = (const float*)d_in[2];
    float* out = (float*)d_out;

    char* ws = (char*)d_ws;
    char* Rp4 = ws;
    char* Qp4 = ws + QB_OFF;
    char* xph = ws + XPH_OFF;

    prep_kernel<<<2368, 256, 0, stream>>>(x, Q, R, Rp4, Qp4, xph);
    fused_kernel<<<512, 256, 65536, stream>>>(xph, Rp4, Qp4, out);
}